// Round 8
// baseline (1872.945 us; speedup 1.0000x reference)
//
#include <hip/hip_runtime.h>

#define BD 256   // batch
#define HD 1024  // hidden
#define KC 2048  // concatenated K = [x | h]
#define LATD 512 // latent
#define OD 128   // output dim
#define TS 100   // seq_len (fixed by problem)

typedef __attribute__((ext_vector_type(8))) short s16x8;
typedef __attribute__((ext_vector_type(4))) float f32x4;

__device__ __forceinline__ float b2f(short s) {
  return __uint_as_float(((unsigned)(unsigned short)s) << 16);
}
__device__ __forceinline__ short f2b(float f) {
  unsigned u = __float_as_uint(f);
  u += 0x7fff + ((u >> 16) & 1);  // RNE
  return (short)(u >> 16);
}
__device__ __forceinline__ float sigm(float x) { return 1.f / (1.f + __expf(-x)); }
__device__ __forceinline__ float tanh_f(float x) { return 1.f - 2.f / (__expf(2.f * x) + 1.f); }

// xh fragment-major chunk index: m -> (mt=m/16, r=m%16), k -> (kc=k/8, e=k%8)
// kq=kc/64, it=(kc/4)%16, q=kc%4; chunk = ((mt*4+kq)*16+it)*64 + q*16 + r
__device__ __forceinline__ size_t xhf_idx(int m, int k) {
  int kc = k >> 3;
  int kq = kc >> 6, it = (kc >> 2) & 15, q = kc & 3;
  int mt = m >> 4, r = m & 15;
  return ((((size_t)mt * 4 + kq) * 16 + it) * 64 + q * 16 + r) * 8 + (k & 7);
}

// ---------------- one-time prep kernels ----------------

__global__ __launch_bounds__(256) void cvt8_k(const float* __restrict__ in,
                                              short* __restrict__ out) {
  int i = (blockIdx.x * 256 + threadIdx.x) * 8;
  f32x4 a = *(const f32x4*)(in + i), b = *(const f32x4*)(in + i + 4);
  s16x8 o;
#pragma unroll
  for (int e = 0; e < 4; ++e) { o[e] = f2b(a[e]); o[4 + e] = f2b(b[e]); }
  *(s16x8*)(out + i) = o;
}

// Fragment-major weight repack (verified r6/r7):
// chunk i = ((bn*64 + kit)*4 + quad)*16 + lan; bn = g*64+bx; k = kit*32+quad*8
__global__ __launch_bounds__(256) void wrep_k(const float* __restrict__ Wih,
                                              const float* __restrict__ Whh,
                                              short* __restrict__ Wt) {
  int i = blockIdx.x * 256 + threadIdx.x;  // chunk id, < 1048576
  int lan = i & 15, quad = (i >> 4) & 3, kit = (i >> 6) & 63, bn = i >> 12;
  int g = bn >> 6, bx = bn & 63;
  int n = g * HD + bx * 16 + lan;
  int k = kit * 32 + quad * 8;
  const float* src = (k < HD) ? (Wih + (size_t)n * HD + k)
                              : (Whh + (size_t)n * HD + (k - HD));
  f32x4 a = *(const f32x4*)src, b = *(const f32x4*)(src + 4);
  s16x8 o;
#pragma unroll
  for (int e = 0; e < 4; ++e) { o[e] = f2b(a[e]); o[4 + e] = f2b(b[e]); }
  *(s16x8*)(Wt + (size_t)i * 8) = o;
}

__global__ __launch_bounds__(256) void bsum_k(const float* __restrict__ bi,
                                              const float* __restrict__ bh,
                                              float* __restrict__ bs) {
  int i = blockIdx.x * 256 + threadIdx.x;
  bs[i] = bi[i] + bh[i];
}

__global__ __launch_bounds__(256) void x0_k(const float* __restrict__ st,
                                            const float* __restrict__ W,
                                            const float* __restrict__ bias,
                                            short* __restrict__ xrow) {
  int j = blockIdx.x * 256 + threadIdx.x;
  float acc = 0.f;
  for (int k = 0; k < OD; ++k) acc += st[k] * W[j * OD + k];
  acc += bias[j];
  xrow[j] = f2b(acc > 0.f ? acc : 0.f);
}

// x-half init: xhf[m][k] = xrow[k], k<1024
__global__ __launch_bounds__(256) void bcast_k(const short* __restrict__ xrow,
                                               short* __restrict__ xhf) {
  int i = blockIdx.x * 256 + threadIdx.x;  // over BD*HD
  int m = i >> 10, k = i & 1023;
  xhf[xhf_idx(m, k)] = xrow[k];
}

// ---------------- head GEMM: out = lrelu(A @ W^T + b), N=1024, M=256 ----------------
// MODE: 0 = fp32 flat [m*1024+col]; 1 = bf16 flat [m*os+oo+col]; 2 = bf16 xhf h-half
template <int K, bool IN_BF16, int MODE>
__global__ __launch_bounds__(256) void fc_mfma(const void* __restrict__ in_,
                                               const float* __restrict__ W,
                                               const float* __restrict__ bias,
                                               void* __restrict__ out_,
                                               int ostride, int ooff) {
  const int tid = threadIdx.x;
  const int w = tid >> 6, lan = tid & 15, quad = (tid & 63) >> 4;
  const int n0 = blockIdx.x * 64;
  const int m0 = blockIdx.y * 64;
  const int arow = m0 + w * 16 + lan;
  f32x4 acc[4] = {};
  for (int k0 = 0; k0 < K; k0 += 32) {
    const int ka = k0 + quad * 8;
    s16x8 af;
    if (IN_BF16) {
      af = *(const s16x8*)((const short*)in_ + arow * K + ka);
    } else {
      const float* ap = (const float*)in_ + arow * K + ka;
      f32x4 a0 = *(const f32x4*)ap, a1 = *(const f32x4*)(ap + 4);
#pragma unroll
      for (int e = 0; e < 4; ++e) { af[e] = f2b(a0[e]); af[4 + e] = f2b(a1[e]); }
    }
#pragma unroll
    for (int nf = 0; nf < 4; ++nf) {
      const float* bp = W + (n0 + nf * 16 + lan) * K + ka;
      f32x4 b0 = *(const f32x4*)bp, b1 = *(const f32x4*)(bp + 4);
      s16x8 bf;
#pragma unroll
      for (int e = 0; e < 4; ++e) { bf[e] = f2b(b0[e]); bf[4 + e] = f2b(b1[e]); }
      acc[nf] = __builtin_amdgcn_mfma_f32_16x16x32_bf16(af, bf, acc[nf], 0, 0, 0);
    }
  }
#pragma unroll
  for (int nf = 0; nf < 4; ++nf) {
    int col = n0 + nf * 16 + lan;
    float bb = bias[col];
#pragma unroll
    for (int j = 0; j < 4; ++j) {
      int m = m0 + w * 16 + quad * 4 + j;
      float v = acc[nf][j] + bb;
      v = v > 0.f ? v : 0.01f * v;
      if (MODE == 0)
        ((float*)out_)[m * 1024 + col] = v;
      else if (MODE == 1)
        ((short*)out_)[m * ostride + ooff + col] = f2b(v);
      else
        ((short*)out_)[xhf_idx(m, HD + col)] = f2b(v);
    }
  }
}

__global__ __launch_bounds__(256) void num_k(const float* __restrict__ n1,
                                             const float* __restrict__ w2,
                                             const float* __restrict__ b2,
                                             float* __restrict__ out) {
  int l = threadIdx.x & 63, w = threadIdx.x >> 6;
  int m = blockIdx.x * 4 + w;
  const float* r = n1 + m * HD + l * 16;
  const float* wv = w2 + l * 16;
  float acc = 0.f;
#pragma unroll
  for (int c = 0; c < 4; ++c) {
    f32x4 a = *(const f32x4*)(r + c * 4), b = *(const f32x4*)(wv + c * 4);
#pragma unroll
    for (int e = 0; e < 4; ++e) acc += a[e] * b[e];
  }
  for (int off = 32; off; off >>= 1) acc += __shfl_down(acc, off);
  if (l == 0) {
    float v = acc + b2[0];
    out[m] = v > 0.f ? v : 0.f;
  }
}

__global__ __launch_bounds__(256) void mass_k(const short* __restrict__ m2,
                                              const float* __restrict__ w3,
                                              const float* __restrict__ b3,
                                              float* __restrict__ out) {
  int l = threadIdx.x & 63, w = threadIdx.x >> 6;
  int m = blockIdx.x * 4 + w;
  const short* r = m2 + m * HD + l * 16;
  s16x8 v0 = *(const s16x8*)r, v1 = *(const s16x8*)(r + 8);
  float z0 = 0.f, z1 = 0.f;
#pragma unroll
  for (int e = 0; e < 8; ++e) {
    float a = b2f(v0[e]), b = b2f(v1[e]);
    z0 += a * w3[l * 16 + e] + b * w3[l * 16 + 8 + e];
    z1 += a * w3[HD + l * 16 + e] + b * w3[HD + l * 16 + 8 + e];
  }
  for (int off = 32; off; off >>= 1) {
    z0 += __shfl_down(z0, off);
    z1 += __shfl_down(z1, off);
  }
  if (l == 0) {
    z0 += b3[0]; z1 += b3[1];
    float mx = fmaxf(z0, z1);
    float e0 = __expf(z0 - mx), e1 = __expf(z1 - mx);
    float s = e0 + e1;
    out[m * 2] = e0 / s;
    out[m * 2 + 1] = e1 / s;
  }
}

// ---------------- fused LSTM step v4: zero-redundancy loads ----------------
// grid (64, 4), blockDim 256 (4 waves). Wave = one K-quarter (kq = w).
// Per k-iter a wave loads 4 A-frags (mt=0..3) + 4 B-frags (g=0..3), all
// contiguous 1 KB, all unique within the block -> per-CU L2 traffic = 512 KB
// floor. 16 MFMA per iter per wave. 2-deep register pipeline.
__global__ __launch_bounds__(256) void lstm_step(
    const short* __restrict__ xhf, float* __restrict__ cbuf,
    const short* __restrict__ Wt, const float* __restrict__ bsum,
    short* __restrict__ xhf_out, short* __restrict__ hs_out,
    float* __restrict__ o_h, float* __restrict__ o_c, int last) {
  __shared__ float red[4 * 64 * 65];  // 66.6 KB: [(kq*64+lane)*65 + c], c<64

  const int tid = threadIdx.x;
  const int kq = tid >> 6, l = tid & 63;
  const int quad = l >> 4, lan = l & 15;
  const int bx = blockIdx.x;       // 16 h-cols
  const int by = blockIdx.y;       // 64 m-rows
  const int m0 = by * 64;
  const int c0 = bx * 16;

  const short* ap[4];
#pragma unroll
  for (int mt = 0; mt < 4; ++mt)
    ap[mt] = xhf + ((size_t)((by * 4 + mt) * 4 + kq) * 16) * 512 + (size_t)l * 8;
  const short* bp[4];
#pragma unroll
  for (int g = 0; g < 4; ++g)
    bp[g] = Wt + ((size_t)(g * 64 + bx) * 64 + kq * 16) * 512 + (size_t)(quad * 16 + lan) * 8;

  f32x4 acc[4][4] = {};  // [mt][g]

  s16x8 aP[4], bP[4], aQ[4], bQ[4];
#pragma unroll
  for (int x = 0; x < 4; ++x) {
    aP[x] = *(const s16x8*)(ap[x]);
    bP[x] = *(const s16x8*)(bp[x]);
    aQ[x] = *(const s16x8*)(ap[x] + 512);
    bQ[x] = *(const s16x8*)(bp[x] + 512);
  }
#pragma unroll
  for (int it = 0; it < 16; ++it) {
    if ((it & 1) == 0) {
#pragma unroll
      for (int g = 0; g < 4; ++g)
#pragma unroll
        for (int mt = 0; mt < 4; ++mt)
          acc[mt][g] = __builtin_amdgcn_mfma_f32_16x16x32_bf16(aP[mt], bP[g], acc[mt][g], 0, 0, 0);
      if (it + 2 < 16) {
        int o = (it + 2) * 512;
#pragma unroll
        for (int x = 0; x < 4; ++x) {
          aP[x] = *(const s16x8*)(ap[x] + o);
          bP[x] = *(const s16x8*)(bp[x] + o);
        }
      }
    } else {
#pragma unroll
      for (int g = 0; g < 4; ++g)
#pragma unroll
        for (int mt = 0; mt < 4; ++mt)
          acc[mt][g] = __builtin_amdgcn_mfma_f32_16x16x32_bf16(aQ[mt], bQ[g], acc[mt][g], 0, 0, 0);
      if (it + 2 < 16) {
        int o = (it + 2) * 512;
#pragma unroll
        for (int x = 0; x < 4; ++x) {
          aQ[x] = *(const s16x8*)(ap[x] + o);
          bQ[x] = *(const s16x8*)(bp[x] + o);
        }
      }
    }
  }

  // stash partials: lane slot = (kq*64+l)*65, c = (mt*4+g)*4 + j
  float* slot = &red[(size_t)(kq * 64 + l) * 65];
#pragma unroll
  for (int mt = 0; mt < 4; ++mt)
#pragma unroll
    for (int g = 0; g < 4; ++g)
      *(f32x4*)(slot + (mt * 4 + g) * 4) = acc[mt][g];
  __syncthreads();

  // epilogue: thread t -> hc = t&15, mb = t>>4; cells mloc = rep*16 + mb
  const int hc = tid & 15, mb = tid >> 4;
  const int eq = mb >> 2, jj = mb & 3;
  const int lane = eq * 16 + hc;
  const int ch = c0 + hc;
  const float bsi = bsum[ch];
  const float bsf = bsum[HD + ch];
  const float bsg = bsum[2 * HD + ch];
  const float bso = bsum[3 * HD + ch];
#pragma unroll
  for (int rep = 0; rep < 4; ++rep) {
    const int mloc = rep * 16 + mb;  // mt = rep, row-in-frag = mb
    float g4[4];
#pragma unroll
    for (int g = 0; g < 4; ++g) {
      float s = 0.f;
#pragma unroll
      for (int k2 = 0; k2 < 4; ++k2)
        s += red[(size_t)(k2 * 64 + lane) * 65 + (rep * 4 + g) * 4 + jj];
      g4[g] = s;
    }
    const int mg = m0 + mloc;
    float gi = g4[0] + bsi;
    float gf = g4[1] + bsf;
    float gg = g4[2] + bsg;
    float go = g4[3] + bso;
    int idx = mg * HD + ch;
    float cn = sigm(gf) * cbuf[idx] + sigm(gi) * tanh_f(gg);
    cbuf[idx] = cn;
    float h = sigm(go) * tanh_f(cn);
    short h16 = f2b(h);
    xhf_out[xhf_idx(mg, ch)] = f2b(h > 0.f ? h : 0.f);  // x-half: relu(h)
    xhf_out[xhf_idx(mg, HD + ch)] = h16;                // h-half
    hs_out[idx] = h16;
    if (last) {
      o_h[idx] = h;
      o_c[idx] = cn;
    }
  }
}

// ---------------- output projection over a CH-step chunk ----------------
__global__ __launch_bounds__(256) void out_proj(const short* __restrict__ hsC,
                                                const short* __restrict__ Wo,
                                                const float* __restrict__ bo,
                                                float* __restrict__ dout, int t0) {
  const int tid = threadIdx.x;
  const int w = tid >> 6, lan = tid & 15, quad = (tid & 63) >> 4;
  const int n0 = blockIdx.x * 64;
  const int m0 = blockIdx.y * 64;
  const short* ap = hsC + (size_t)(m0 + w * 16 + lan) * HD;
  f32x4 acc[4] = {};
#pragma unroll 2
  for (int k0 = 0; k0 < HD; k0 += 32) {
    const int ka = k0 + quad * 8;
    s16x8 a = *(const s16x8*)(ap + ka);
#pragma unroll
    for (int nf = 0; nf < 4; ++nf) {
      s16x8 b = *(const s16x8*)(Wo + (size_t)(n0 + nf * 16 + lan) * HD + ka);
      acc[nf] = __builtin_amdgcn_mfma_f32_16x16x32_bf16(a, b, acc[nf], 0, 0, 0);
    }
  }
#pragma unroll
  for (int nf = 0; nf < 4; ++nf) {
    int col = n0 + nf * 16 + lan;
    float bb = bo[col];
#pragma unroll
    for (int j = 0; j < 4; ++j) {
      int m = m0 + w * 16 + quad * 4 + j;
      int tc = m >> 8, b = m & 255;
      dout[(size_t)(b * TS + t0 + tc) * OD + col] = acc[nf][j] + bb;
    }
  }
}

extern "C" void kernel_launch(void* const* d_in, const int* in_sizes, int n_in,
                              void* d_out, int out_size, void* d_ws, size_t ws_size,
                              hipStream_t stream) {
  static const int exp_sizes[26] = {
      131072, 131072, 128, 524288, 1024, 524288, 1024, 131072, 1024,
      4194304, 4194304, 4096, 4096, 131072, 128, 524288, 1024, 1024, 1,
      524288, 1024, 1048576, 1024, 2048, 2, 1};
  if (n_in < 26) return;
  for (int i = 0; i < 26; ++i)
    if (in_sizes[i] != exp_sizes[i]) return;

  const float* enc_out = (const float*)d_in[0];
  const float* enc_hid = (const float*)d_in[1];
  const float* start_tok = (const float*)d_in[2];
  const float* l2h_w = (const float*)d_in[3];
  const float* l2h_b = (const float*)d_in[4];
  const float* l2h2_w = (const float*)d_in[5];
  const float* l2h2_b = (const float*)d_in[6];
  const float* emb_w = (const float*)d_in[7];
  const float* emb_b = (const float*)d_in[8];
  const float* Wih_f = (const float*)d_in[9];
  const float* Whh_f = (const float*)d_in[10];
  const float* bih = (const float*)d_in[11];
  const float* bhh = (const float*)d_in[12];
  const float* outw_f = (const float*)d_in[13];
  const float* outb = (const float*)d_in[14];
  const float* seq_w = (const float*)d_in[15];
  const float* seq_b = (const float*)d_in[16];
  const float* seq2_w = (const float*)d_in[17];
  const float* seq2_b = (const float*)d_in[18];
  const float* mass_w = (const float*)d_in[19];
  const float* mass_b = (const float*)d_in[20];
  const float* mass2_w = (const float*)d_in[21];
  const float* mass2_b = (const float*)d_in[22];
  const float* mass3_w = (const float*)d_in[23];
  const float* mass3_b = (const float*)d_in[24];

  // ---- workspace layout ----
  char* p = (char*)d_ws;
  float* c_buf = (float*)p;  p += (size_t)BD * HD * 4;        // 1 MB
  float* bsum = (float*)p;   p += (size_t)4 * HD * 4;         // 16 KB
  float* n1 = (float*)p;     p += (size_t)BD * HD * 4;        // 1 MB
  short* m1 = (short*)p;     p += (size_t)BD * HD * 2;        // 512 KB
  short* m2 = (short*)p;     p += (size_t)BD * HD * 2;        // 512 KB
  short* xrow = (short*)p;   p += (size_t)HD * 2;             // 2 KB
  short* xhA = (short*)p;    p += (size_t)BD * KC * 2;        // 1 MB
  short* xhB = (short*)p;    p += (size_t)BD * KC * 2;        // 1 MB
  short* Wt = (short*)p;     p += (size_t)4 * HD * KC * 2;    // 16 MB
  short* outw = (short*)p;   p += (size_t)OD * HD * 2;        // 256 KB
  short* hsC = (short*)p;    // CH * BD * HD bf16
  size_t fixed_bytes = (size_t)(p - (char*)d_ws);
  const size_t step_bytes = (size_t)BD * HD * 2;
  int CH = 0;
  const int cands[7] = {25, 20, 10, 5, 4, 2, 1};
  for (int ci = 0; ci < 7; ++ci) {
    if (fixed_bytes + (size_t)cands[ci] * step_bytes <= ws_size) { CH = cands[ci]; break; }
  }
  if (CH == 0) return;

  float* dout = (float*)d_out;
  float* o_dec = dout;                       // [B][TS][OD]
  float* o_h = dout + (size_t)BD * TS * OD;  // [1][B][HD]
  float* o_c = o_h + (size_t)BD * HD;        // [1][B][HD]
  float* o_num = o_c + (size_t)BD * HD;      // [B][1]
  float* o_mass = o_num + BD;                // [B][2]

  // prep
  wrep_k<<<4096, 256, 0, stream>>>(Wih_f, Whh_f, Wt);
  cvt8_k<<<OD * HD / 2048, 256, 0, stream>>>(outw_f, outw);
  bsum_k<<<16, 256, 0, stream>>>(bih, bhh, bsum);
  x0_k<<<4, 256, 0, stream>>>(start_tok, emb_w, emb_b, xrow);
  bcast_k<<<BD * HD / 256, 256, 0, stream>>>(xrow, xhA);

  // heads + initial state
  dim3 fcg(16, 4);
  fc_mfma<LATD, false, 2><<<fcg, 256, 0, stream>>>(enc_hid, l2h_w, l2h_b, xhA, 0, 0);
  fc_mfma<LATD, false, 0><<<fcg, 256, 0, stream>>>(enc_hid, l2h2_w, l2h2_b, c_buf, 0, 0);
  fc_mfma<LATD, false, 0><<<fcg, 256, 0, stream>>>(enc_out, seq_w, seq_b, n1, 0, 0);
  fc_mfma<LATD, false, 1><<<fcg, 256, 0, stream>>>(enc_out, mass_w, mass_b, m1, HD, 0);
  fc_mfma<HD, true, 1><<<fcg, 256, 0, stream>>>(m1, mass2_w, mass2_b, m2, HD, 0);
  num_k<<<64, 256, 0, stream>>>(n1, seq2_w, seq2_b, o_num);
  mass_k<<<64, 256, 0, stream>>>(m2, mass3_w, mass3_b, o_mass);

  // LSTM scan
  short* xs[2] = {xhA, xhB};
  for (int t = 0; t < TS; ++t) {
    int i = t & 1;
    lstm_step<<<dim3(64, 4), 256, 0, stream>>>(
        xs[i], c_buf, Wt, bsum, xs[1 - i],
        hsC + (size_t)(t % CH) * BD * HD, o_h, o_c, (t == TS - 1) ? 1 : 0);
    if ((t + 1) % CH == 0) {
      out_proj<<<dim3(2, CH * BD / 64), 256, 0, stream>>>(hsC, outw, outb, o_dec, t + 1 - CH);
    }
  }
}